// Round 4
// baseline (105.052 us; speedup 1.0000x reference)
//
#include <hip/hip_runtime.h>

#define NTOK 65536   // B*S = 16*4096
#define HD 128
#define NE 8
#define FD 256
#define NG (NTOK / 64)   // 1024 token groups of 64

typedef __attribute__((ext_vector_type(4))) float f32x4;
typedef __attribute__((ext_vector_type(2))) float f32x2;
typedef __attribute__((ext_vector_type(8))) short s16x8;
typedef __attribute__((ext_vector_type(2))) unsigned u32x2;

__device__ __forceinline__ unsigned short f2bf(float f) {
  union { float f; unsigned u; } v; v.f = f;
  unsigned r = v.u + 0x7fffu + ((v.u >> 16) & 1u);   // RNE
  return (unsigned short)(r >> 16);
}
__device__ __forceinline__ float bf2f(unsigned u16) {
  union { unsigned u; float f; } v; v.u = u16 << 16;
  return v.f;
}

// ---------------------------------------------------------------------------
// prep: repack W1/W2 into MFMA fragment-linear bf16 layout (A- and B-fragment
// lane maps coincide, so the same layout serves the transposed GEMMs).
// Wb1f idx = (((e*4+ks)*16+cf)*64+lane)*8+j ; k=ks*32+(lane>>4)*8+j ; f=cf*16+(lane&15)
// Wb2f idx = (((e*8+ks)*8+cf)*64+lane)*8+j  ; kf over FD ; ho=cf*16+(lane&15)
// ---------------------------------------------------------------------------
__global__ __launch_bounds__(256) void prep_kernel(
    const float* __restrict__ W1, const float* __restrict__ W2,
    unsigned short* __restrict__ Wb1f, unsigned short* __restrict__ Wb2f) {
  int gid = blockIdx.x * 256 + threadIdx.x;
  int stride = gridDim.x * 256;
  for (int idx = gid; idx < NE * HD * FD; idx += stride) {
    int j = idx & 7, lane = (idx >> 3) & 63, cf = (idx >> 9) & 15,
        ks = (idx >> 13) & 3, e = idx >> 15;
    int k = ks * 32 + (lane >> 4) * 8 + j;
    int f = cf * 16 + (lane & 15);
    Wb1f[idx] = f2bf(W1[((size_t)e * HD + k) * FD + f]);
  }
  for (int idx = gid; idx < NE * FD * HD; idx += stride) {
    int j = idx & 7, lane = (idx >> 3) & 63, cf = (idx >> 9) & 7,
        ks = (idx >> 12) & 7, e = idx >> 15;
    int kf = ks * 32 + (lane >> 4) * 8 + j;
    int ho = cf * 16 + (lane & 15);
    Wb2f[idx] = f2bf(W2[((size_t)e * FD + kf) * HD + ho]);
  }
}

// ---------------------------------------------------------------------------
// gate: logits, +gumbel+bias, top-2, 2-way softmax. Writes per-token choices
// (tok_e packed, tok_w) and per-block expert histogram. NO atomics.
// ---------------------------------------------------------------------------
__global__ __launch_bounds__(256) void gate_kernel(
    const float* __restrict__ x, const float* __restrict__ gumbel,
    const float* __restrict__ gateW, const float* __restrict__ gateB,
    int* __restrict__ blkcnt, int* __restrict__ tok_e, float* __restrict__ tok_w) {
  __shared__ __attribute__((aligned(16))) char gws[4160];
  __shared__ unsigned char tE1[64], tE2[64];
  int tid = threadIdx.x;
  for (int i = tid; i < HD * NE; i += 256) {
    int h = i >> 3, e = i & 7;
    *(float*)(gws + h * 32 + (h >> 5) * 16 + e * 4) = gateW[i];
  }
  __syncthreads();
  int lane = tid & 63, w = tid >> 6;
  int q = lane & 3;                 // quarter of the H dim
  int ti = w * 16 + (lane >> 2);    // token within block
  int t = blockIdx.x * 64 + ti;
  f32x4 accA = {0.f, 0.f, 0.f, 0.f}, accB = {0.f, 0.f, 0.f, 0.f};
  const f32x4* xp = (const f32x4*)(x + (size_t)t * HD + q * 32);
#pragma unroll
  for (int i = 0; i < 8; ++i) {
    f32x4 xv = xp[i];
    int h0 = q * 32 + i * 4;
#pragma unroll
    for (int c = 0; c < 4; ++c) {
      float xs = xv[c];
      unsigned bo = (unsigned)((h0 + c) * 32 + q * 16);
      accA += xs * *(const f32x4*)(gws + bo);
      accB += xs * *(const f32x4*)(gws + bo + 16);
    }
  }
#pragma unroll
  for (int d = 1; d <= 2; d <<= 1) {
#pragma unroll
    for (int c = 0; c < 4; ++c) {
      accA[c] += __shfl_xor(accA[c], d);
      accB[c] += __shfl_xor(accB[c], d);
    }
  }
  if (q == 0) {
    float n[8];
#pragma unroll
    for (int c = 0; c < 4; ++c) { n[c] = accA[c]; n[4 + c] = accB[c]; }
#pragma unroll
    for (int e2 = 0; e2 < 8; ++e2) n[e2] += gateB[e2] + gumbel[(size_t)t * 8 + e2];
    int i1 = 0; float v1 = n[0];
#pragma unroll
    for (int e2 = 1; e2 < 8; ++e2) if (n[e2] > v1) { v1 = n[e2]; i1 = e2; }
    int i2 = (i1 == 0) ? 1 : 0; float v2 = n[i2];
#pragma unroll
    for (int e2 = 0; e2 < 8; ++e2) if (e2 != i1 && n[e2] > v2) { v2 = n[e2]; i2 = e2; }
    float p2 = 1.f / (1.f + __expf(v1 - v2));  // softmax over {v1,v2}
    float p1 = 1.f - p2;
    tE1[ti] = (unsigned char)i1; tE2[ti] = (unsigned char)i2;
    tok_w[(size_t)t * 2 + 0] = p1;
    tok_w[(size_t)t * 2 + 1] = p2;
  }
  __syncthreads();
  int e1v = tE1[lane], e2v = tE2[lane];
#pragma unroll
  for (int ee = 0; ee < 2; ++ee) {
    int e = w * 2 + ee;
    int c = __popcll(__ballot(e1v == e)) + __popcll(__ballot(e2v == e));
    if (lane == 0) blkcnt[blockIdx.x * 8 + e] = c;
  }
  if (tid < 64) tok_e[blockIdx.x * 64 + tid] = (int)tE1[tid] | ((int)tE2[tid] << 4);
}

// ---------------------------------------------------------------------------
// scan: exclusive prefix over the 1024 group histograms -> blkoff, totals -> counts
// ---------------------------------------------------------------------------
__global__ __launch_bounds__(256) void scan_kernel(
    const int* __restrict__ blkcnt, int* __restrict__ blkoff, int* __restrict__ counts) {
  __shared__ int part[256];
  int tid = threadIdx.x;
  int e = tid & 7, c = tid >> 3;    // 32 chunks x 8 experts
  int s = 0;
#pragma unroll 4
  for (int i = 0; i < 32; ++i) s += blkcnt[(c * 32 + i) * 8 + e];
  part[tid] = s;
  __syncthreads();
  if (tid < 8) {
    int run = 0;
    for (int cc = 0; cc < 32; ++cc) {
      int tv = part[cc * 8 + tid];
      part[cc * 8 + tid] = run;
      run += tv;
    }
    counts[tid] = run;
  }
  __syncthreads();
  int base = part[tid];
  for (int i = 0; i < 32; ++i) {
    int g = c * 32 + i;
    blkoff[g * 8 + e] = base;
    base += blkcnt[g * 8 + e];
  }
}

// ---------------------------------------------------------------------------
// scatter: ballot-rank within each 64-token group + blkoff base -> lists/tok_es
// ---------------------------------------------------------------------------
__global__ __launch_bounds__(256) void scatter_kernel(
    const int* __restrict__ tok_e, const int* __restrict__ blkoff,
    int* __restrict__ lists, int* __restrict__ tok_es) {
  int tid = threadIdx.x, lane = tid & 63, w = tid >> 6;
  int g = blockIdx.x * 4 + w;
  int tg = g * 64 + lane;
  int pk = tok_e[tg];
  int e1 = pk & 15, e2 = pk >> 4;
  unsigned long long lt = (((unsigned long long)1) << lane) - 1;
  int s1 = 0, s2 = 0;
#pragma unroll
  for (int e = 0; e < NE; ++e) {
    unsigned long long m1 = __ballot(e1 == e);
    unsigned long long m2 = __ballot(e2 == e);
    if (e1 == e) s1 = blkoff[g * 8 + e] + __popcll(m1 & lt);
    if (e2 == e) s2 = blkoff[g * 8 + e] + __popcll(m1) + __popcll(m2 & lt);
  }
  lists[e1 * NTOK + s1] = tg;
  tok_es[(size_t)tg * 2 + 0] = (e1 << 24) | s1;
  lists[e2 * NTOK + s2] = tg;
  tok_es[(size_t)tg * 2 + 1] = (e2 << 24) | s2;
}

// ---------------------------------------------------------------------------
// grouped expert MLP, LDS-free transposed form.
// Wave mt owns 16 tokens. GEMM1': h^T = W1^T(A) @ x^T(B) -> lane holds 4
// consecutive f per fragment (16 f-tiles). bias+relu+pack in regs (hpk).
// GEMM2': out^T = W2^T(A) @ h^T(B); B-frags assembled from hpk via shfl.
// Epilogue: 4 consecutive ho per lane -> packed 8B global stores.
// ---------------------------------------------------------------------------
__global__ __launch_bounds__(256) void moe_mlp_kernel(
    const float* __restrict__ x,
    const unsigned short* __restrict__ Wb1f, const unsigned short* __restrict__ Wb2f,
    const float* __restrict__ b1, const float* __restrict__ b2,
    const int* __restrict__ counts, const int* __restrict__ lists,
    unsigned short* __restrict__ out_slots) {
  int e = blockIdx.x >> 10;
  int m0 = (blockIdx.x & 1023) << 6;
  int cnt = counts[e];
  if (m0 >= cnt) return;
  int base_e = 0;
#pragma unroll
  for (int i = 0; i < NE; ++i) if (i < e) base_e += counts[i];
  int tid = threadIdx.x, lane = tid & 63, mt = tid >> 6;
  int q = lane >> 4, m = lane & 15;
  int ltk = mt * 16 + m;            // local token index in the 64-tile
  int sidx = m0 + ltk;              // slot within expert
  int tokid = lists[e * NTOK + (sidx < cnt ? sidx : 0)];
  const float* xrow = x + (size_t)tokid * HD;

  // -------- GEMM1': 16 f-tiles, K=128 (ks=0..3)
  f32x4 acc1[16];
#pragma unroll
  for (int i = 0; i < 16; ++i) acc1[i] = (f32x4){0.f, 0.f, 0.f, 0.f};
  const s16x8* w1p = (const s16x8*)Wb1f + (size_t)(e * 4) * 16 * 64 + lane;
#pragma unroll
  for (int ks = 0; ks < 4; ++ks) {
    f32x4 xv0 = *(const f32x4*)(xrow + ks * 32 + q * 8);
    f32x4 xv1 = *(const f32x4*)(xrow + ks * 32 + q * 8 + 4);
    s16x8 bx;
#pragma unroll
    for (int c = 0; c < 4; ++c) {
      bx[c] = (short)f2bf(xv0[c]);
      bx[4 + c] = (short)f2bf(xv1[c]);
    }
#pragma unroll
    for (int ft = 0; ft < 16; ++ft) {
      s16x8 af = w1p[(ks * 16 + ft) * 64];
      acc1[ft] = __builtin_amdgcn_mfma_f32_16x16x32_bf16(af, bx, acc1[ft], 0, 0, 0);
    }
  }
  // bias + relu -> packed bf16 pairs (lane holds f = ft*16 + q*4 + {0..3})
  unsigned hpk[16][2];
#pragma unroll
  for (int ft = 0; ft < 16; ++ft) {
    f32x4 bv = *(const f32x4*)(b1 + e * FD + ft * 16 + q * 4);
    float v0 = acc1[ft][0] + bv[0]; v0 = v0 > 0.f ? v0 : 0.f;
    float v1 = acc1[ft][1] + bv[1]; v1 = v1 > 0.f ? v1 : 0.f;
    float v2 = acc1[ft][2] + bv[2]; v2 = v2 > 0.f ? v2 : 0.f;
    float v3 = acc1[ft][3] + bv[3]; v3 = v3 > 0.f ? v3 : 0.f;
    hpk[ft][0] = (unsigned)f2bf(v0) | ((unsigned)f2bf(v1) << 16);
    hpk[ft][1] = (unsigned)f2bf(v2) | ((unsigned)f2bf(v3) << 16);
  }
  // -------- GEMM2': 8 ho-tiles, K=256 (ks=0..7)
  f32x4 acc2[8];
#pragma unroll
  for (int i = 0; i < 8; ++i) acc2[i] = (f32x4){0.f, 0.f, 0.f, 0.f};
  int src0 = ((q & 1) << 5) | m;    // lane (q'=2*(q&1), m)
  int src1 = src0 + 16;             // lane (q'=2*(q&1)+1, m)
  bool hi = (q >> 1) != 0;          // which f-tile of the ks pair this lane needs
  const s16x8* w2p = (const s16x8*)Wb2f + (size_t)(e * 8) * 8 * 64 + lane;
#pragma unroll
  for (int ks = 0; ks < 8; ++ks) {
    unsigned a0 = hpk[ks * 2][0],     a1 = hpk[ks * 2][1];
    unsigned b0 = hpk[ks * 2 + 1][0], b1v = hpk[ks * 2 + 1][1];
    unsigned sa00 = (unsigned)__shfl((int)a0, src0);
    unsigned sa10 = (unsigned)__shfl((int)a1, src0);
    unsigned sa01 = (unsigned)__shfl((int)a0, src1);
    unsigned sa11 = (unsigned)__shfl((int)a1, src1);
    unsigned sb00 = (unsigned)__shfl((int)b0, src0);
    unsigned sb10 = (unsigned)__shfl((int)b1v, src0);
    unsigned sb01 = (unsigned)__shfl((int)b0, src1);
    unsigned sb11 = (unsigned)__shfl((int)b1v, src1);
    union { unsigned u[4]; s16x8 v; } bh;
    bh.u[0] = hi ? sb00 : sa00;
    bh.u[1] = hi ? sb10 : sa10;
    bh.u[2] = hi ? sb01 : sa01;
    bh.u[3] = hi ? sb11 : sa11;
#pragma unroll
    for (int ht = 0; ht < 8; ++ht) {
      s16x8 af = w2p[(ks * 8 + ht) * 64];
      acc2[ht] = __builtin_amdgcn_mfma_f32_16x16x32_bf16(af, bh.v, acc2[ht], 0, 0, 0);
    }
  }
  // -------- epilogue: +b2, pack, 8B stores (lane: ho = ht*16 + q*4 + {0..3})
  if (sidx < cnt) {
    unsigned short* dst = out_slots + (size_t)(base_e + sidx) * HD;
#pragma unroll
    for (int ht = 0; ht < 8; ++ht) {
      f32x4 bv = *(const f32x4*)(b2 + e * HD + ht * 16 + q * 4);
      float v0 = acc2[ht][0] + bv[0];
      float v1 = acc2[ht][1] + bv[1];
      float v2 = acc2[ht][2] + bv[2];
      float v3 = acc2[ht][3] + bv[3];
      u32x2 p;
      p[0] = (unsigned)f2bf(v0) | ((unsigned)f2bf(v1) << 16);
      p[1] = (unsigned)f2bf(v2) | ((unsigned)f2bf(v3) << 16);
      *(u32x2*)(dst + ht * 16 + q * 4) = p;
    }
  }
}

// ---------------------------------------------------------------------------
// LN: y = x + w0*slot0 + w1*slot1 ; LayerNorm over H=128 ; one wave per token
// ---------------------------------------------------------------------------
__global__ __launch_bounds__(256) void ln_kernel(
    const float* __restrict__ x, const unsigned short* __restrict__ out_slots,
    const int* __restrict__ counts, const int* __restrict__ tok_es,
    const float* __restrict__ tok_w, const float* __restrict__ lng,
    const float* __restrict__ lnb, float* __restrict__ out) {
  int tid = threadIdx.x, lane = tid & 63, w = tid >> 6;
  int t = blockIdx.x * 4 + w;
  int es0 = tok_es[(size_t)t * 2], es1 = tok_es[(size_t)t * 2 + 1];
  float w0 = tok_w[(size_t)t * 2], w1 = tok_w[(size_t)t * 2 + 1];
  int e0 = es0 >> 24, e1 = es1 >> 24;
  int b0 = 0, b1 = 0, a = 0;
#pragma unroll
  for (int i = 0; i < NE; ++i) {
    if (i == e0) b0 = a;
    if (i == e1) b1 = a;
    a += counts[i];
  }
  size_t gs0 = (size_t)(b0 + (es0 & 0xffffff)) * HD;
  size_t gs1 = (size_t)(b1 + (es1 & 0xffffff)) * HD;
  f32x2 xv = ((const f32x2*)(x + (size_t)t * HD))[lane];
  unsigned s0 = ((const unsigned*)(out_slots + gs0))[lane];
  unsigned s1 = ((const unsigned*)(out_slots + gs1))[lane];
  float y0 = xv[0] + w0 * bf2f(s0 & 0xffffu) + w1 * bf2f(s1 & 0xffffu);
  float y1 = xv[1] + w0 * bf2f(s0 >> 16) + w1 * bf2f(s1 >> 16);
  float sm = y0 + y1, ss = y0 * y0 + y1 * y1;
#pragma unroll
  for (int d = 1; d < 64; d <<= 1) { sm += __shfl_xor(sm, d); ss += __shfl_xor(ss, d); }
  float mu = sm * (1.f / 128.f);
  float var = ss * (1.f / 128.f) - mu * mu;
  float rstd = rsqrtf(var + 1e-5f);
  f32x2 g = ((const f32x2*)lng)[lane];
  f32x2 bb = ((const f32x2*)lnb)[lane];
  f32x2 o;
  o[0] = (y0 - mu) * rstd * g[0] + bb[0];
  o[1] = (y1 - mu) * rstd * g[1] + bb[1];
  ((f32x2*)(out + (size_t)t * HD))[lane] = o;
}

extern "C" void kernel_launch(void* const* d_in, const int* in_sizes, int n_in,
                              void* d_out, int out_size, void* d_ws, size_t ws_size,
                              hipStream_t stream) {
  const float* x     = (const float*)d_in[0];
  const float* gum   = (const float*)d_in[1];
  const float* gateW = (const float*)d_in[2];
  const float* gateB = (const float*)d_in[3];
  const float* W1    = (const float*)d_in[4];
  const float* b1    = (const float*)d_in[5];
  const float* W2    = (const float*)d_in[6];
  const float* b2    = (const float*)d_in[7];
  const float* lng   = (const float*)d_in[8];
  const float* lnb   = (const float*)d_in[9];
  float* out = (float*)d_out;

  char* ws = (char*)d_ws;
  int* counts = (int*)ws;                      ws += 256;
  int* tok_es = (int*)ws;                      ws += (size_t)2 * NTOK * 4;
  float* tok_w = (float*)ws;                   ws += (size_t)2 * NTOK * 4;
  int* lists = (int*)ws;                       ws += (size_t)NE * NTOK * 4;
  unsigned short* Wb1f = (unsigned short*)ws;  ws += (size_t)NE * HD * FD * 2;
  unsigned short* Wb2f = (unsigned short*)ws;  ws += (size_t)NE * FD * HD * 2;
  unsigned short* out_slots = (unsigned short*)ws; ws += (size_t)2 * NTOK * HD * 2;
  int* blkcnt = (int*)ws;                      ws += (size_t)NG * 8 * 4;
  int* blkoff = (int*)ws;                      ws += (size_t)NG * 8 * 4;
  int* tok_e  = (int*)ws;                      ws += (size_t)NTOK * 4;

  prep_kernel<<<dim3(256), dim3(256), 0, stream>>>(W1, W2, Wb1f, Wb2f);
  gate_kernel<<<dim3(NG), dim3(256), 0, stream>>>(
      x, gum, gateW, gateB, blkcnt, tok_e, tok_w);
  scan_kernel<<<dim3(1), dim3(256), 0, stream>>>(blkcnt, blkoff, counts);
  scatter_kernel<<<dim3(NG / 4), dim3(256), 0, stream>>>(tok_e, blkoff, lists, tok_es);
  moe_mlp_kernel<<<dim3(NE * 1024), dim3(256), 0, stream>>>(
      x, Wb1f, Wb2f, b1, b2, counts, lists, out_slots);
  ln_kernel<<<dim3(NTOK / 4), dim3(256), 0, stream>>>(
      x, out_slots, counts, tok_es, tok_w, lng, lnb, out);
}

// Round 5
// 86.237 us; speedup vs baseline: 1.2182x; 1.2182x over previous
//
#include <hip/hip_runtime.h>

#define NTOK 65536   // B*S = 16*4096
#define HD 128
#define NE 8
#define FD 256
#define NG (NTOK / 64)   // 1024 token groups of 64

typedef __attribute__((ext_vector_type(4))) float f32x4;
typedef __attribute__((ext_vector_type(2))) float f32x2;
typedef __attribute__((ext_vector_type(8))) short s16x8;
typedef __attribute__((ext_vector_type(2))) unsigned u32x2;

__device__ __forceinline__ unsigned short f2bf(float f) {
  union { float f; unsigned u; } v; v.f = f;
  unsigned r = v.u + 0x7fffu + ((v.u >> 16) & 1u);   // RNE
  return (unsigned short)(r >> 16);
}
__device__ __forceinline__ float bf2f(unsigned u16) {
  union { unsigned u; float f; } v; v.u = u16 << 16;
  return v.f;
}

// ---------------------------------------------------------------------------
// prep: repack W1/W2 into MFMA fragment-linear bf16 layout (A- and B-fragment
// lane maps coincide: frag dim = lane&15, k = (lane>>4)*8+j).
// Wb1f idx = (((e*4+ks)*16+cf)*64+lane)*8+j ; k=ks*32+(lane>>4)*8+j ; f=cf*16+(lane&15)
// Wb2f idx = (((e*8+ks)*8+cf)*64+lane)*8+j  ; kf over FD ; ho=cf*16+(lane&15)
// ---------------------------------------------------------------------------
__global__ __launch_bounds__(256) void prep_kernel(
    const float* __restrict__ W1, const float* __restrict__ W2,
    unsigned short* __restrict__ Wb1f, unsigned short* __restrict__ Wb2f) {
  int gid = blockIdx.x * 256 + threadIdx.x;
  int stride = gridDim.x * 256;
  for (int idx = gid; idx < NE * HD * FD; idx += stride) {
    int j = idx & 7, lane = (idx >> 3) & 63, cf = (idx >> 9) & 15,
        ks = (idx >> 13) & 3, e = idx >> 15;
    int k = ks * 32 + (lane >> 4) * 8 + j;
    int f = cf * 16 + (lane & 15);
    Wb1f[idx] = f2bf(W1[((size_t)e * HD + k) * FD + f]);
  }
  for (int idx = gid; idx < NE * FD * HD; idx += stride) {
    int j = idx & 7, lane = (idx >> 3) & 63, cf = (idx >> 9) & 7,
        ks = (idx >> 12) & 7, e = idx >> 15;
    int kf = ks * 32 + (lane >> 4) * 8 + j;
    int ho = cf * 16 + (lane & 15);
    Wb2f[idx] = f2bf(W2[((size_t)e * FD + kf) * HD + ho]);
  }
}

// ---------------------------------------------------------------------------
// gate: logits, +gumbel+bias, top-2, 2-way softmax. Writes per-token choices
// (tok_e packed, tok_w) and per-block expert histogram. NO atomics.
// ---------------------------------------------------------------------------
__global__ __launch_bounds__(256) void gate_kernel(
    const float* __restrict__ x, const float* __restrict__ gumbel,
    const float* __restrict__ gateW, const float* __restrict__ gateB,
    int* __restrict__ blkcnt, int* __restrict__ tok_e, float* __restrict__ tok_w) {
  __shared__ __attribute__((aligned(16))) char gws[4160];
  __shared__ unsigned char tE1[64], tE2[64];
  int tid = threadIdx.x;
  for (int i = tid; i < HD * NE; i += 256) {
    int h = i >> 3, e = i & 7;
    *(float*)(gws + h * 32 + (h >> 5) * 16 + e * 4) = gateW[i];
  }
  __syncthreads();
  int lane = tid & 63, w = tid >> 6;
  int q = lane & 3;                 // quarter of the H dim
  int ti = w * 16 + (lane >> 2);    // token within block
  int t = blockIdx.x * 64 + ti;
  f32x4 accA = {0.f, 0.f, 0.f, 0.f}, accB = {0.f, 0.f, 0.f, 0.f};
  const f32x4* xp = (const f32x4*)(x + (size_t)t * HD + q * 32);
#pragma unroll
  for (int i = 0; i < 8; ++i) {
    f32x4 xv = xp[i];
    int h0 = q * 32 + i * 4;
#pragma unroll
    for (int c = 0; c < 4; ++c) {
      float xs = xv[c];
      unsigned bo = (unsigned)((h0 + c) * 32 + q * 16);
      accA += xs * *(const f32x4*)(gws + bo);
      accB += xs * *(const f32x4*)(gws + bo + 16);
    }
  }
#pragma unroll
  for (int d = 1; d <= 2; d <<= 1) {
#pragma unroll
    for (int c = 0; c < 4; ++c) {
      accA[c] += __shfl_xor(accA[c], d);
      accB[c] += __shfl_xor(accB[c], d);
    }
  }
  if (q == 0) {
    float n[8];
#pragma unroll
    for (int c = 0; c < 4; ++c) { n[c] = accA[c]; n[4 + c] = accB[c]; }
#pragma unroll
    for (int e2 = 0; e2 < 8; ++e2) n[e2] += gateB[e2] + gumbel[(size_t)t * 8 + e2];
    int i1 = 0; float v1 = n[0];
#pragma unroll
    for (int e2 = 1; e2 < 8; ++e2) if (n[e2] > v1) { v1 = n[e2]; i1 = e2; }
    int i2 = (i1 == 0) ? 1 : 0; float v2 = n[i2];
#pragma unroll
    for (int e2 = 0; e2 < 8; ++e2) if (e2 != i1 && n[e2] > v2) { v2 = n[e2]; i2 = e2; }
    float p2 = 1.f / (1.f + __expf(v1 - v2));  // softmax over {v1,v2}
    float p1 = 1.f - p2;
    tE1[ti] = (unsigned char)i1; tE2[ti] = (unsigned char)i2;
    tok_w[(size_t)t * 2 + 0] = p1;
    tok_w[(size_t)t * 2 + 1] = p2;
  }
  __syncthreads();
  int e1v = tE1[lane], e2v = tE2[lane];
#pragma unroll
  for (int ee = 0; ee < 2; ++ee) {
    int e = w * 2 + ee;
    int c = __popcll(__ballot(e1v == e)) + __popcll(__ballot(e2v == e));
    if (lane == 0) blkcnt[blockIdx.x * 8 + e] = c;
  }
  if (tid < 64) tok_e[blockIdx.x * 64 + tid] = (int)tE1[tid] | ((int)tE2[tid] << 4);
}

// ---------------------------------------------------------------------------
// scan: exclusive prefix over the 1024 group histograms -> blkoff, totals -> counts
// ---------------------------------------------------------------------------
__global__ __launch_bounds__(256) void scan_kernel(
    const int* __restrict__ blkcnt, int* __restrict__ blkoff, int* __restrict__ counts) {
  __shared__ int part[256];
  int tid = threadIdx.x;
  int e = tid & 7, c = tid >> 3;    // 32 chunks x 8 experts
  int s = 0;
#pragma unroll 4
  for (int i = 0; i < 32; ++i) s += blkcnt[(c * 32 + i) * 8 + e];
  part[tid] = s;
  __syncthreads();
  if (tid < 8) {
    int run = 0;
    for (int cc = 0; cc < 32; ++cc) {
      int tv = part[cc * 8 + tid];
      part[cc * 8 + tid] = run;
      run += tv;
    }
    counts[tid] = run;
  }
  __syncthreads();
  int base = part[tid];
  for (int i = 0; i < 32; ++i) {
    int g = c * 32 + i;
    blkoff[g * 8 + e] = base;
    base += blkcnt[g * 8 + e];
  }
}

// ---------------------------------------------------------------------------
// scatter: ballot-rank within each 64-token group + blkoff base -> lists/tok_es
// ---------------------------------------------------------------------------
__global__ __launch_bounds__(256) void scatter_kernel(
    const int* __restrict__ tok_e, const int* __restrict__ blkoff,
    int* __restrict__ lists, int* __restrict__ tok_es) {
  int tid = threadIdx.x, lane = tid & 63, w = tid >> 6;
  int g = blockIdx.x * 4 + w;
  int tg = g * 64 + lane;
  int pk = tok_e[tg];
  int e1 = pk & 15, e2 = pk >> 4;
  unsigned long long lt = (((unsigned long long)1) << lane) - 1;
  int s1 = 0, s2 = 0;
#pragma unroll
  for (int e = 0; e < NE; ++e) {
    unsigned long long m1 = __ballot(e1 == e);
    unsigned long long m2 = __ballot(e2 == e);
    if (e1 == e) s1 = blkoff[g * 8 + e] + __popcll(m1 & lt);
    if (e2 == e) s2 = blkoff[g * 8 + e] + __popcll(m1) + __popcll(m2 & lt);
  }
  lists[e1 * NTOK + s1] = tg;
  tok_es[(size_t)tg * 2 + 0] = (e1 << 24) | s1;
  lists[e2 * NTOK + s2] = tg;
  tok_es[(size_t)tg * 2 + 1] = (e2 << 24) | s2;
}

// ---------------------------------------------------------------------------
// grouped expert MLP, hybrid: 64-token tile, waves split f/ho ranges
// (weights amortized 4x), transposed GEMMs so epilogues pack 4 consecutive
// outputs per lane: h -> ds_write_b64, out -> direct 8B global stores.
// GEMM1': h^T = W1^T(A) @ x^T(B from LDS)   wave w: f in [w*64, w*64+64)
// GEMM2': out^T = W2^T(A) @ h^T(B from LDS) wave w: ho in [w*32, w*32+32)
// ---------------------------------------------------------------------------
__global__ __launch_bounds__(256) void moe_mlp_kernel(
    const float* __restrict__ x,
    const unsigned short* __restrict__ Wb1f, const unsigned short* __restrict__ Wb2f,
    const float* __restrict__ b1, const float* __restrict__ b2,
    const int* __restrict__ counts, const int* __restrict__ lists,
    unsigned short* __restrict__ out_slots) {
  __shared__ char xl[64 * 256];   // 16KB: x tile bf16 [tok][H], XOR-swizzled
  __shared__ char hl[64 * 512];   // 32KB: h tile bf16 [tok][F], XOR-swizzled
  __shared__ int tok[64];
  int e = blockIdx.x >> 10;
  int m0 = (blockIdx.x & 1023) << 6;
  int cnt = counts[e];
  if (m0 >= cnt) return;
  int base_e = 0;
#pragma unroll
  for (int i = 0; i < NE; ++i) if (i < e) base_e += counts[i];
  int tid = threadIdx.x;
  if (tid < 64) {
    int m = m0 + tid;
    tok[tid] = lists[e * NTOK + (m < cnt ? m : m0)];
  }
  __syncthreads();
  {
    int r = tid >> 2, q4 = tid & 3;
    const f32x4* xp = (const f32x4*)(x + (size_t)tok[r] * HD + q4 * 32);
#pragma unroll
    for (int i = 0; i < 4; ++i) {
      f32x4 v0 = xp[i * 2], v1 = xp[i * 2 + 1];
      s16x8 pk;
#pragma unroll
      for (int c = 0; c < 4; ++c) { pk[c] = (short)f2bf(v0[c]); pk[4 + c] = (short)f2bf(v1[c]); }
      unsigned byte = ((unsigned)(r * 256 + q4 * 64 + i * 16)) ^ ((unsigned)(r & 7) << 4);
      *(s16x8*)(xl + byte) = pk;
    }
  }
  __syncthreads();
  int lane = tid & 63, w = tid >> 6;
  int q = lane >> 4, m = lane & 15;
  // -------- GEMM1': acc1[cf][tt], C row = f, col = token
  f32x4 acc1[4][4];
#pragma unroll
  for (int a = 0; a < 4; ++a)
#pragma unroll
    for (int b = 0; b < 4; ++b) acc1[a][b] = (f32x4){0.f, 0.f, 0.f, 0.f};
  const s16x8* w1p = (const s16x8*)Wb1f + (size_t)(e * 4) * 16 * 64 + lane;
#pragma unroll
  for (int ks = 0; ks < 4; ++ks) {
    s16x8 bfx[4], wa[4];
#pragma unroll
    for (int tt = 0; tt < 4; ++tt) {
      int tk = tt * 16 + m;
      unsigned byte = ((unsigned)(tk * 256 + ks * 64 + q * 16)) ^ ((unsigned)(tk & 7) << 4);
      bfx[tt] = *(const s16x8*)(xl + byte);
    }
#pragma unroll
    for (int cf = 0; cf < 4; ++cf) wa[cf] = w1p[(ks * 16 + w * 4 + cf) * 64];
#pragma unroll
    for (int cf = 0; cf < 4; ++cf)
#pragma unroll
      for (int tt = 0; tt < 4; ++tt)
        acc1[cf][tt] = __builtin_amdgcn_mfma_f32_16x16x32_bf16(wa[cf], bfx[tt], acc1[cf][tt], 0, 0, 0);
  }
  // bias+relu in regs, pack 4 consecutive f -> one ds_write_b64
#pragma unroll
  for (int cf = 0; cf < 4; ++cf) {
    int f0 = (w * 4 + cf) * 16 + q * 4;
    f32x4 bv = *(const f32x4*)(b1 + e * FD + f0);
#pragma unroll
    for (int tt = 0; tt < 4; ++tt) {
      int tk = tt * 16 + m;
      float v0 = acc1[cf][tt][0] + bv[0]; v0 = v0 > 0.f ? v0 : 0.f;
      float v1 = acc1[cf][tt][1] + bv[1]; v1 = v1 > 0.f ? v1 : 0.f;
      float v2 = acc1[cf][tt][2] + bv[2]; v2 = v2 > 0.f ? v2 : 0.f;
      float v3 = acc1[cf][tt][3] + bv[3]; v3 = v3 > 0.f ? v3 : 0.f;
      u32x2 p;
      p[0] = (unsigned)f2bf(v0) | ((unsigned)f2bf(v1) << 16);
      p[1] = (unsigned)f2bf(v2) | ((unsigned)f2bf(v3) << 16);
      unsigned byte = ((unsigned)(tk * 512 + f0 * 2)) ^ ((unsigned)(tk & 7) << 4);
      *(u32x2*)(hl + byte) = p;
    }
  }
  __syncthreads();
  // -------- GEMM2': acc2[c2][tt], C row = ho, col = token
  f32x4 acc2[2][4];
#pragma unroll
  for (int a = 0; a < 2; ++a)
#pragma unroll
    for (int b = 0; b < 4; ++b) acc2[a][b] = (f32x4){0.f, 0.f, 0.f, 0.f};
  const s16x8* w2p = (const s16x8*)Wb2f + (size_t)(e * 8) * 8 * 64 + lane;
#pragma unroll
  for (int ks = 0; ks < 8; ++ks) {
    s16x8 bfh[4], wa[2];
#pragma unroll
    for (int tt = 0; tt < 4; ++tt) {
      int tk = tt * 16 + m;
      unsigned byte = ((unsigned)(tk * 512 + ks * 64 + q * 16)) ^ ((unsigned)(tk & 7) << 4);
      bfh[tt] = *(const s16x8*)(hl + byte);
    }
#pragma unroll
    for (int c2 = 0; c2 < 2; ++c2) wa[c2] = w2p[(ks * 8 + w * 2 + c2) * 64];
#pragma unroll
    for (int c2 = 0; c2 < 2; ++c2)
#pragma unroll
      for (int tt = 0; tt < 4; ++tt)
        acc2[c2][tt] = __builtin_amdgcn_mfma_f32_16x16x32_bf16(wa[c2], bfh[tt], acc2[c2][tt], 0, 0, 0);
  }
  // -------- epilogue: +b2, pack 4 consecutive ho -> direct 8B global stores
#pragma unroll
  for (int c2 = 0; c2 < 2; ++c2) {
    int ho0 = (w * 2 + c2) * 16 + q * 4;
    f32x4 bv = *(const f32x4*)(b2 + e * HD + ho0);
#pragma unroll
    for (int tt = 0; tt < 4; ++tt) {
      int tk = tt * 16 + m;
      int sidx = m0 + tk;
      if (sidx < cnt) {
        u32x2 p;
        p[0] = (unsigned)f2bf(acc2[c2][tt][0] + bv[0]) | ((unsigned)f2bf(acc2[c2][tt][1] + bv[1]) << 16);
        p[1] = (unsigned)f2bf(acc2[c2][tt][2] + bv[2]) | ((unsigned)f2bf(acc2[c2][tt][3] + bv[3]) << 16);
        *(u32x2*)(out_slots + (size_t)(base_e + sidx) * HD + ho0) = p;
      }
    }
  }
}

// ---------------------------------------------------------------------------
// LN: y = x + w0*slot0 + w1*slot1 ; LayerNorm over H=128 ; one wave per token
// ---------------------------------------------------------------------------
__global__ __launch_bounds__(256) void ln_kernel(
    const float* __restrict__ x, const unsigned short* __restrict__ out_slots,
    const int* __restrict__ counts, const int* __restrict__ tok_es,
    const float* __restrict__ tok_w, const float* __restrict__ lng,
    const float* __restrict__ lnb, float* __restrict__ out) {
  int tid = threadIdx.x, lane = tid & 63, w = tid >> 6;
  int t = blockIdx.x * 4 + w;
  int es0 = tok_es[(size_t)t * 2], es1 = tok_es[(size_t)t * 2 + 1];
  float w0 = tok_w[(size_t)t * 2], w1 = tok_w[(size_t)t * 2 + 1];
  int e0 = es0 >> 24, e1 = es1 >> 24;
  int b0 = 0, b1 = 0, a = 0;
#pragma unroll
  for (int i = 0; i < NE; ++i) {
    if (i == e0) b0 = a;
    if (i == e1) b1 = a;
    a += counts[i];
  }
  size_t gs0 = (size_t)(b0 + (es0 & 0xffffff)) * HD;
  size_t gs1 = (size_t)(b1 + (es1 & 0xffffff)) * HD;
  f32x2 xv = ((const f32x2*)(x + (size_t)t * HD))[lane];
  unsigned s0 = ((const unsigned*)(out_slots + gs0))[lane];
  unsigned s1 = ((const unsigned*)(out_slots + gs1))[lane];
  float y0 = xv[0] + w0 * bf2f(s0 & 0xffffu) + w1 * bf2f(s1 & 0xffffu);
  float y1 = xv[1] + w0 * bf2f(s0 >> 16) + w1 * bf2f(s1 >> 16);
  float sm = y0 + y1, ss = y0 * y0 + y1 * y1;
#pragma unroll
  for (int d = 1; d < 64; d <<= 1) { sm += __shfl_xor(sm, d); ss += __shfl_xor(ss, d); }
  float mu = sm * (1.f / 128.f);
  float var = ss * (1.f / 128.f) - mu * mu;
  float rstd = rsqrtf(var + 1e-5f);
  f32x2 g = ((const f32x2*)lng)[lane];
  f32x2 bb = ((const f32x2*)lnb)[lane];
  f32x2 o;
  o[0] = (y0 - mu) * rstd * g[0] + bb[0];
  o[1] = (y1 - mu) * rstd * g[1] + bb[1];
  ((f32x2*)(out + (size_t)t * HD))[lane] = o;
}

extern "C" void kernel_launch(void* const* d_in, const int* in_sizes, int n_in,
                              void* d_out, int out_size, void* d_ws, size_t ws_size,
                              hipStream_t stream) {
  const float* x     = (const float*)d_in[0];
  const float* gum   = (const float*)d_in[1];
  const float* gateW = (const float*)d_in[2];
  const float* gateB = (const float*)d_in[3];
  const float* W1    = (const float*)d_in[4];
  const float* b1    = (const float*)d_in[5];
  const float* W2    = (const float*)d_in[6];
  const float* b2    = (const float*)d_in[7];
  const float* lng   = (const float*)d_in[8];
  const float* lnb   = (const float*)d_in[9];
  float* out = (float*)d_out;

  char* ws = (char*)d_ws;
  int* counts = (int*)ws;                      ws += 256;
  int* tok_es = (int*)ws;                      ws += (size_t)2 * NTOK * 4;
  float* tok_w = (float*)ws;                   ws += (size_t)2 * NTOK * 4;
  int* lists = (int*)ws;                       ws += (size_t)NE * NTOK * 4;
  unsigned short* Wb1f = (unsigned short*)ws;  ws += (size_t)NE * HD * FD * 2;
  unsigned short* Wb2f = (unsigned short*)ws;  ws += (size_t)NE * FD * HD * 2;
  unsigned short* out_slots = (unsigned short*)ws; ws += (size_t)2 * NTOK * HD * 2;
  int* blkcnt = (int*)ws;                      ws += (size_t)NG * 8 * 4;
  int* blkoff = (int*)ws;                      ws += (size_t)NG * 8 * 4;
  int* tok_e  = (int*)ws;                      ws += (size_t)NTOK * 4;

  prep_kernel<<<dim3(256), dim3(256), 0, stream>>>(W1, W2, Wb1f, Wb2f);
  gate_kernel<<<dim3(NG), dim3(256), 0, stream>>>(
      x, gum, gateW, gateB, blkcnt, tok_e, tok_w);
  scan_kernel<<<dim3(1), dim3(256), 0, stream>>>(blkcnt, blkoff, counts);
  scatter_kernel<<<dim3(NG / 4), dim3(256), 0, stream>>>(tok_e, blkoff, lists, tok_es);
  moe_mlp_kernel<<<dim3(NE * 1024), dim3(256), 0, stream>>>(
      x, Wb1f, Wb2f, b1, b2, counts, lists, out_slots);
  ln_kernel<<<dim3(NTOK / 4), dim3(256), 0, stream>>>(
      x, out_slots, counts, tok_es, tok_w, lng, lnb, out);
}